// Round 14
// baseline (276.139 us; speedup 1.0000x reference)
//
#include <hip/hip_runtime.h>

#define NN 50000
#define NE 800000
#define DD 128

#define CAP 64                                     // slots per node bucket
#define QPAD 8                                     // cursor64: 1 bin per 64B
#define FIX_SCALE 16777216.0f                      // 2^24
#define LOW40 ((1ULL << 40) - 1)
#define NWELEM 16384                               // per weight matrix
#define GEMM_GRID ((NN + 127) / 128)               // 391
#define PLACE_GRID ((NE + 255) / 256)              // 3125

typedef __attribute__((ext_vector_type(8))) short short8;
typedef __attribute__((ext_vector_type(4))) float floatx4;
typedef __attribute__((ext_vector_type(2))) unsigned int uint2v;
typedef __attribute__((ext_vector_type(4))) _Float16 half4;
typedef __attribute__((ext_vector_type(8))) _Float16 half8;

// ---------------- bf16 split (truncation; err ~2^-16 rel) ----------------

__device__ __forceinline__ void split_trunc(float x, short& hi, short& lo) {
    unsigned uh = __float_as_uint(x) >> 16;
    hi = (short)uh;
    float r = x - __uint_as_float(uh << 16);
    lo = (short)(__float_as_uint(r) >> 16);
}

// ---------------- fused init: zero atomic bins + split both W matrices ----------------

__global__ void init_prep(unsigned long long* __restrict__ cursor64,
                          const float* __restrict__ W1, const float* __restrict__ W2,
                          unsigned short* __restrict__ w1hi, unsigned short* __restrict__ w1lo,
                          unsigned short* __restrict__ w2hi, unsigned short* __restrict__ w2lo) {
    int t = blockIdx.x * blockDim.x + threadIdx.x;
    if (t < NN) cursor64[t * QPAD] = 0ULL;
    int u = t - NN;
    if (u >= 0 && u < 2 * NWELEM) {
        int which = u >> 14;
        int idx = u & (NWELEM - 1);
        int k = idx >> 7, n = idx & 127;
        const float* W = which ? W2 : W1;
        unsigned short* whi = which ? w2hi : w1hi;
        unsigned short* wlo = which ? w2lo : w1lo;
        short h, l;
        split_trunc(W[idx], h, l);
        whi[n * DD + k] = (unsigned short)h;
        wlo[n * DD + k] = (unsigned short)l;
    }
}

// ---------------- GEMM core: out[m,128] (fp16) = (relu?)in @ W (*dis?) ----------------

template <bool RELU, bool SCALE, typename InT>
__device__ __forceinline__ void gemm_core(int bid, const InT* __restrict__ in,
                                          const unsigned short* __restrict__ whi,
                                          const unsigned short* __restrict__ wlo,
                                          const float* __restrict__ dis,
                                          _Float16* __restrict__ out) {
    int lane = threadIdx.x & 63;
    int wid = threadIdx.x >> 6;
    int cg = wid & 1;
    int rg = wid >> 1;
    int l16 = lane & 15;
    int quad = lane >> 4;
    int koff_base = quad * 8;

    short8 bhi[4][4], blo[4][4];
#pragma unroll
    for (int t = 0; t < 4; t++) {
        int n = cg * 64 + t * 16 + l16;
#pragma unroll
        for (int ks = 0; ks < 4; ks++) {
            int koff = ks * 32 + koff_base;
            bhi[t][ks] = *(const short8*)(whi + n * DD + koff);
            blo[t][ks] = *(const short8*)(wlo + n * DD + koff);
        }
    }

#pragma unroll
    for (int chunk = 0; chunk < 4; chunk++) {
        int base = bid * 128 + chunk * 32 + rg * 16;
        int m = base + l16;
        int mld = (m < NN) ? m : 0;
        const InT* xr = in + (size_t)mld * DD;

        short8 ahi[4], alo[4];
#pragma unroll
        for (int ks = 0; ks < 4; ks++) {
            int koff = ks * 32 + koff_base;
            float v[8];
            if constexpr (sizeof(InT) == 4) {
                float4 a0 = *(const float4*)(xr + koff);
                float4 a1 = *(const float4*)(xr + koff + 4);
                v[0] = a0.x; v[1] = a0.y; v[2] = a0.z; v[3] = a0.w;
                v[4] = a1.x; v[5] = a1.y; v[6] = a1.z; v[7] = a1.w;
            } else {
                half8 a = *(const half8*)(xr + koff);
#pragma unroll
                for (int j = 0; j < 8; j++) v[j] = (float)a[j];
            }
#pragma unroll
            for (int j = 0; j < 8; j++) {
                float xv = RELU ? fmaxf(v[j], 0.0f) : v[j];
                short h, l;
                split_trunc(xv, h, l);
                ahi[ks][j] = h;
                alo[ks][j] = l;
            }
        }

        floatx4 acc[4];
#pragma unroll
        for (int t = 0; t < 4; t++) acc[t] = (floatx4)(0.0f);

#pragma unroll
        for (int ks = 0; ks < 4; ks++) {
#pragma unroll
            for (int t = 0; t < 4; t++) {
                acc[t] = __builtin_amdgcn_mfma_f32_16x16x32_bf16(ahi[ks], bhi[t][ks], acc[t], 0, 0, 0);
                acc[t] = __builtin_amdgcn_mfma_f32_16x16x32_bf16(alo[ks], bhi[t][ks], acc[t], 0, 0, 0);
                acc[t] = __builtin_amdgcn_mfma_f32_16x16x32_bf16(ahi[ks], blo[t][ks], acc[t], 0, 0, 0);
            }
        }

#pragma unroll
        for (int r = 0; r < 4; r++) {
            int rowm = base + quad * 4 + r;
            if (rowm < NN) {
                float dsc = SCALE ? dis[rowm] : 1.0f;
                _Float16* o = out + (size_t)rowm * DD + cg * 64 + l16;
#pragma unroll
                for (int t = 0; t < 4; t++) o[t * 16] = (_Float16)(acc[t][r] * dsc);
            }
        }
    }
}

// ---------------- placement core: ONE packed atomic per edge ----------------

__device__ __forceinline__ void place_core(int e, const int* __restrict__ row,
                                           const int* __restrict__ col,
                                           const float* __restrict__ ew,
                                           unsigned long long* __restrict__ cursor64,
                                           uint2v* __restrict__ epk) {
    if (e >= NE) return;
    int c = col[e];
    float w = ew[e];
    unsigned q = (unsigned)(w * FIX_SCALE + 0.5f);
    unsigned long long old = atomicAdd(&cursor64[c * QPAD], (1ULL << 40) | (unsigned long long)q);
    int rank = min((int)(old >> 40), CAP - 1);     // clamp: memory safety on overflow
    uint2v p;
    p.x = (unsigned)(row[e] * DD);                 // pre-scaled gather index
    p.y = __float_as_uint(w);
    epk[(c << 6) + rank] = p;
}

// ---------------- FUSED: edge placement (long pole, dispatched FIRST) + gemm1 ----------------

__global__ __launch_bounds__(256) void gemm1_place(const float* __restrict__ x,
                                                   const unsigned short* __restrict__ w1hi,
                                                   const unsigned short* __restrict__ w1lo,
                                                   _Float16* __restrict__ g,
                                                   const int* __restrict__ row,
                                                   const int* __restrict__ col,
                                                   const float* __restrict__ ew,
                                                   unsigned long long* __restrict__ cursor64,
                                                   uint2v* __restrict__ epk) {
    if (blockIdx.x < PLACE_GRID) {
        int e = blockIdx.x * 256 + threadIdx.x;
        place_core(e, row, col, ew, cursor64, epk);
    } else {
        gemm_core<false, false, float>(blockIdx.x - PLACE_GRID, x, w1hi, w1lo, nullptr, g);
    }
}

// layer-2 GEMM wrapper (dis folded in epilogue)
__global__ __launch_bounds__(256, 2) void gemm2(const _Float16* __restrict__ in,
                                                const unsigned short* __restrict__ whi,
                                                const unsigned short* __restrict__ wlo,
                                                const float* __restrict__ dis,
                                                _Float16* __restrict__ out) {
    gemm_core<true, true, _Float16>(blockIdx.x, in, whi, wlo, dis, out);
}

// ---------------- node_dis + g1 scaling: dis, endarr, g1 *= dis ----------------

__global__ __launch_bounds__(256) void node_dis_scale(const unsigned long long* __restrict__ cursor64,
                                                      float* __restrict__ dis,
                                                      int* __restrict__ endarr,
                                                      _Float16* __restrict__ g) {
    int t = blockIdx.x * blockDim.x + threadIdx.x;
    int i = t >> 4, sub = t & 15;
    if (i >= NN) return;
    unsigned long long cv = cursor64[i * QPAD];    // broadcast across the 16 lanes
    float deg = 1.0f + (float)(cv & LOW40) * (1.0f / FIX_SCALE);  // +1 self-loop
    float d = rsqrtf(deg);
    if (sub == 0) {
        dis[i] = d;
        endarr[i] = (i << 6) + min((int)(cv >> 40), CAP);
    }
    half8* gp = (half8*)(g + (size_t)i * DD + sub * 8);
    half8 v = *gp;
#pragma unroll
    for (int j = 0; j < 8; j++) v[j] = (_Float16)((float)v[j] * d);
    *gp = v;
}

// ---------------- bucket gather aggregation (fp16 g, f32 accumulate) ----------------
// One wave per node; half-waves on alternating slots, 4x unrolled -> 8 gathers in flight.
// epk loads non-temporal (streamed once; keep L2 for g rows).
// out[i] = b + dis_i * (sum_e ew_e * g[row_e] + g[i]),  g = dis*h

template <typename OutT>
__global__ __launch_bounds__(256) void agg_half(const int* __restrict__ endarr,
                                                const uint2v* __restrict__ epk,
                                                const _Float16* __restrict__ g,
                                                const float* __restrict__ dis,
                                                const float* __restrict__ bias,
                                                OutT* __restrict__ out) {
    int i = (blockIdx.x * blockDim.x + threadIdx.x) >> 6;   // node
    int lane = threadIdx.x & 63;
    int s = lane & 31;
    int half = lane >> 5;
    if (i >= NN) return;

    half4 gv = *(const half4*)(g + (size_t)i * DD + s * 4);  // self-loop term g_i
    float4 bb = ((const float4*)bias)[s];
    float d = dis[i];

    float ax = 0.0f, ay = 0.0f, az = 0.0f, aw = 0.0f;

    int start = i << 6;
    int end = endarr[i];
    int j = start + half;
    for (; j + 6 < end; j += 8) {
        uint2v p0 = __builtin_nontemporal_load(&epk[j]);
        uint2v p1 = __builtin_nontemporal_load(&epk[j + 2]);
        uint2v p2 = __builtin_nontemporal_load(&epk[j + 4]);
        uint2v p3 = __builtin_nontemporal_load(&epk[j + 6]);
        half4 v0 = *(const half4*)(g + p0.x + s * 4);
        half4 v1 = *(const half4*)(g + p1.x + s * 4);
        half4 v2 = *(const half4*)(g + p2.x + s * 4);
        half4 v3 = *(const half4*)(g + p3.x + s * 4);
        float n0 = __uint_as_float(p0.y), n1 = __uint_as_float(p1.y);
        float n2 = __uint_as_float(p2.y), n3 = __uint_as_float(p3.y);
        ax = fmaf(n0, (float)v0.x, ax); ay = fmaf(n0, (float)v0.y, ay);
        az = fmaf(n0, (float)v0.z, az); aw = fmaf(n0, (float)v0.w, aw);
        ax = fmaf(n1, (float)v1.x, ax); ay = fmaf(n1, (float)v1.y, ay);
        az = fmaf(n1, (float)v1.z, az); aw = fmaf(n1, (float)v1.w, aw);
        ax = fmaf(n2, (float)v2.x, ax); ay = fmaf(n2, (float)v2.y, ay);
        az = fmaf(n2, (float)v2.z, az); aw = fmaf(n2, (float)v2.w, aw);
        ax = fmaf(n3, (float)v3.x, ax); ay = fmaf(n3, (float)v3.y, ay);
        az = fmaf(n3, (float)v3.z, az); aw = fmaf(n3, (float)v3.w, aw);
    }
    for (; j < end; j += 2) {
        uint2v p = __builtin_nontemporal_load(&epk[j]);
        float nm = __uint_as_float(p.y);
        half4 v = *(const half4*)(g + p.x + s * 4);
        ax = fmaf(nm, (float)v.x, ax); ay = fmaf(nm, (float)v.y, ay);
        az = fmaf(nm, (float)v.z, az); aw = fmaf(nm, (float)v.w, aw);
    }

    ax += __shfl_xor(ax, 32);
    ay += __shfl_xor(ay, 32);
    az += __shfl_xor(az, 32);
    aw += __shfl_xor(aw, 32);

    if (half == 0) {
        float ox = bb.x + d * (ax + (float)gv.x);
        float oy = bb.y + d * (ay + (float)gv.y);
        float oz = bb.z + d * (az + (float)gv.z);
        float ow = bb.w + d * (aw + (float)gv.w);
        if constexpr (sizeof(OutT) == 2) {
            half4 o;
            o.x = (_Float16)ox; o.y = (_Float16)oy;
            o.z = (_Float16)oz; o.w = (_Float16)ow;
            *(half4*)(out + (size_t)i * DD + s * 4) = o;    // out1: re-read by gemm2, keep cached
        } else {
            floatx4 o;
            o.x = ox; o.y = oy; o.z = oz; o.w = ow;
            __builtin_nontemporal_store(o, (floatx4*)(out + (size_t)i * DD) + s);  // final: never re-read
        }
    }
}

// ---------------- launch ----------------

extern "C" void kernel_launch(void* const* d_in, const int* in_sizes, int n_in,
                              void* d_out, int out_size, void* d_ws, size_t ws_size,
                              hipStream_t stream) {
    const float* x  = (const float*)d_in[0];
    const int*   ei = (const int*)d_in[1];
    const float* ew = (const float*)d_in[2];
    const float* W1 = (const float*)d_in[3];
    const float* b1 = (const float*)d_in[4];
    const float* W2 = (const float*)d_in[5];
    const float* b2 = (const float*)d_in[6];
    float* out = (float*)d_out;

    // workspace layout (4B words)
    float* ws      = (float*)d_ws;
    float* dis     = ws;                                        // [0, 50000)
    int*   endarr  = (int*)(ws + 50000);                        // [50000, 100000)
    unsigned long long* cursor64 = (unsigned long long*)(ws + 100000);  // NN*QPAD ull = 800000 words
    uint2v* epk    = (uint2v*)(ws + 900000);                    // NN*CAP uint2 = 6.4M words
    _Float16* gbuf = (_Float16*)(ws + 7300000);                 // NN*DD fp16 = 3.2M words
    unsigned short* wt1hi = (unsigned short*)(ws + 10500000);   // 8192 words each
    unsigned short* wt1lo = (unsigned short*)(ws + 10508192);
    unsigned short* wt2hi = (unsigned short*)(ws + 10516384);
    unsigned short* wt2lo = (unsigned short*)(ws + 10524576);
    _Float16* out1 = (_Float16*)(ws + 10532768);                // NN*DD fp16 = 3.2M words
    // total ~13.73M words ~= 54.9 MB

    const int* rowi = ei;
    const int* coli = ei + NE;

    // ---- 1: zero bins + split W1/W2 ----
    init_prep<<<(NN + 2 * NWELEM + 255) / 256, 256, 0, stream>>>(
        cursor64, W1, W2, wt1hi, wt1lo, wt2hi, wt2lo);

    // ---- 2: FUSED edge placement (first) + gemm1 (h1 = x@W1, unscaled) ----
    gemm1_place<<<PLACE_GRID + GEMM_GRID, 256, 0, stream>>>(
        x, wt1hi, wt1lo, gbuf, rowi, coli, ew, cursor64, epk);

    // ---- 3: dis/endarr + g1 *= dis ----
    node_dis_scale<<<(NN * 16) / 256, 256, 0, stream>>>(cursor64, dis, endarr, gbuf);

    const int agg_grid = (NN * 64) / 256 + 1;

    // ---- 4: out1 = b1 + dis*(edge_sum + g1)  (fp16) ----
    agg_half<_Float16><<<agg_grid, 256, 0, stream>>>(endarr, epk, gbuf, dis, b1, out1);

    // ---- 5: g2 = (relu(out1)@W2)*dis  (fp16) ----
    gemm2<<<GEMM_GRID, 256, 0, stream>>>(out1, wt2hi, wt2lo, dis, gbuf);

    // ---- 6: out = b2 + dis*(edge_sum + g2)  (f32) ----
    agg_half<float><<<agg_grid, 256, 0, stream>>>(endarr, epk, gbuf, dis, b2, out);
}

// Round 15
// 236.709 us; speedup vs baseline: 1.1666x; 1.1666x over previous
//
#include <hip/hip_runtime.h>

#define NN 50000
#define NE 800000
#define DD 128

#define CAP 64                                     // slots per node bucket
#define QPAD 8                                     // cursor64: 1 bin per 64B
#define FIX_SCALE 16777216.0f                      // 2^24
#define LOW40 ((1ULL << 40) - 1)
#define NWELEM 16384                               // per weight matrix
#define GEMM_GRID ((NN + 127) / 128)               // 391
#define EPT 4                                      // edges per place thread
#define PLACE_T (NE / EPT)                         // 200000 place threads
#define PLACE_GRID ((PLACE_T + 255) / 256)         // 782

typedef __attribute__((ext_vector_type(8))) short short8;
typedef __attribute__((ext_vector_type(4))) float floatx4;
typedef __attribute__((ext_vector_type(4))) _Float16 half4;
typedef __attribute__((ext_vector_type(8))) _Float16 half8;

// ---------------- bf16 split (truncation; err ~2^-16 rel) ----------------

__device__ __forceinline__ void split_trunc(float x, short& hi, short& lo) {
    unsigned uh = __float_as_uint(x) >> 16;
    hi = (short)uh;
    float r = x - __uint_as_float(uh << 16);
    lo = (short)(__float_as_uint(r) >> 16);
}

// ---------------- fused init: zero atomic bins + split both W matrices ----------------

__global__ void init_prep(unsigned long long* __restrict__ cursor64,
                          const float* __restrict__ W1, const float* __restrict__ W2,
                          unsigned short* __restrict__ w1hi, unsigned short* __restrict__ w1lo,
                          unsigned short* __restrict__ w2hi, unsigned short* __restrict__ w2lo) {
    int t = blockIdx.x * blockDim.x + threadIdx.x;
    if (t < NN) cursor64[t * QPAD] = 0ULL;
    int u = t - NN;
    if (u >= 0 && u < 2 * NWELEM) {
        int which = u >> 14;
        int idx = u & (NWELEM - 1);
        int k = idx >> 7, n = idx & 127;
        const float* W = which ? W2 : W1;
        unsigned short* whi = which ? w2hi : w1hi;
        unsigned short* wlo = which ? w2lo : w1lo;
        short h, l;
        split_trunc(W[idx], h, l);
        whi[n * DD + k] = (unsigned short)h;
        wlo[n * DD + k] = (unsigned short)l;
    }
}

// ---------------- GEMM core: out[m,128] (fp16) = (relu?)in @ W (*dis?) ----------------

template <bool RELU, bool SCALE, typename InT>
__device__ __forceinline__ void gemm_core(int bid, const InT* __restrict__ in,
                                          const unsigned short* __restrict__ whi,
                                          const unsigned short* __restrict__ wlo,
                                          const float* __restrict__ dis,
                                          _Float16* __restrict__ out) {
    int lane = threadIdx.x & 63;
    int wid = threadIdx.x >> 6;
    int cg = wid & 1;
    int rg = wid >> 1;
    int l16 = lane & 15;
    int quad = lane >> 4;
    int koff_base = quad * 8;

    short8 bhi[4][4], blo[4][4];
#pragma unroll
    for (int t = 0; t < 4; t++) {
        int n = cg * 64 + t * 16 + l16;
#pragma unroll
        for (int ks = 0; ks < 4; ks++) {
            int koff = ks * 32 + koff_base;
            bhi[t][ks] = *(const short8*)(whi + n * DD + koff);
            blo[t][ks] = *(const short8*)(wlo + n * DD + koff);
        }
    }

#pragma unroll
    for (int chunk = 0; chunk < 4; chunk++) {
        int base = bid * 128 + chunk * 32 + rg * 16;
        int m = base + l16;
        int mld = (m < NN) ? m : 0;
        const InT* xr = in + (size_t)mld * DD;

        short8 ahi[4], alo[4];
#pragma unroll
        for (int ks = 0; ks < 4; ks++) {
            int koff = ks * 32 + koff_base;
            float v[8];
            if constexpr (sizeof(InT) == 4) {
                float4 a0 = *(const float4*)(xr + koff);
                float4 a1 = *(const float4*)(xr + koff + 4);
                v[0] = a0.x; v[1] = a0.y; v[2] = a0.z; v[3] = a0.w;
                v[4] = a1.x; v[5] = a1.y; v[6] = a1.z; v[7] = a1.w;
            } else {
                half8 a = *(const half8*)(xr + koff);
#pragma unroll
                for (int j = 0; j < 8; j++) v[j] = (float)a[j];
            }
#pragma unroll
            for (int j = 0; j < 8; j++) {
                float xv = RELU ? fmaxf(v[j], 0.0f) : v[j];
                short h, l;
                split_trunc(xv, h, l);
                ahi[ks][j] = h;
                alo[ks][j] = l;
            }
        }

        floatx4 acc[4];
#pragma unroll
        for (int t = 0; t < 4; t++) acc[t] = (floatx4)(0.0f);

#pragma unroll
        for (int ks = 0; ks < 4; ks++) {
#pragma unroll
            for (int t = 0; t < 4; t++) {
                acc[t] = __builtin_amdgcn_mfma_f32_16x16x32_bf16(ahi[ks], bhi[t][ks], acc[t], 0, 0, 0);
                acc[t] = __builtin_amdgcn_mfma_f32_16x16x32_bf16(alo[ks], bhi[t][ks], acc[t], 0, 0, 0);
                acc[t] = __builtin_amdgcn_mfma_f32_16x16x32_bf16(ahi[ks], blo[t][ks], acc[t], 0, 0, 0);
            }
        }

#pragma unroll
        for (int r = 0; r < 4; r++) {
            int rowm = base + quad * 4 + r;
            if (rowm < NN) {
                float dsc = SCALE ? dis[rowm] : 1.0f;
                _Float16* o = out + (size_t)rowm * DD + cg * 64 + l16;
#pragma unroll
                for (int t = 0; t < 4; t++) o[t * 16] = (_Float16)(acc[t][r] * dsc);
            }
        }
    }
}

// ---------------- placement core: EPT edges per thread, 4 atomics in flight ----------------

__device__ __forceinline__ void place_core4(int tid, const int* __restrict__ row,
                                            const int* __restrict__ col,
                                            const float* __restrict__ ew,
                                            unsigned long long* __restrict__ cursor64,
                                            uint2* __restrict__ epk) {
    if (tid >= PLACE_T) return;
    int c[EPT], r[EPT];
    float w[EPT];
    unsigned long long old[EPT];
#pragma unroll
    for (int k = 0; k < EPT; k++) {
        int e = tid + k * PLACE_T;                 // coalesced within wave
        c[k] = col[e];
        r[k] = row[e];
        w[k] = ew[e];
    }
#pragma unroll
    for (int k = 0; k < EPT; k++) {
        unsigned q = (unsigned)(w[k] * FIX_SCALE + 0.5f);
        old[k] = atomicAdd(&cursor64[c[k] * QPAD], (1ULL << 40) | (unsigned long long)q);
    }
#pragma unroll
    for (int k = 0; k < EPT; k++) {
        int rank = min((int)(old[k] >> 40), CAP - 1);   // clamp: memory safety
        uint2 p;
        p.x = (unsigned)(r[k] * DD);               // pre-scaled gather index
        p.y = __float_as_uint(w[k]);
        epk[(c[k] << 6) + rank] = p;
    }
}

// ---------------- FUSED: gemm1 (independent of graph) + edge placement ----------------

__global__ __launch_bounds__(256) void gemm1_place(const float* __restrict__ x,
                                                   const unsigned short* __restrict__ w1hi,
                                                   const unsigned short* __restrict__ w1lo,
                                                   _Float16* __restrict__ g,
                                                   const int* __restrict__ row,
                                                   const int* __restrict__ col,
                                                   const float* __restrict__ ew,
                                                   unsigned long long* __restrict__ cursor64,
                                                   uint2* __restrict__ epk) {
    if (blockIdx.x < GEMM_GRID) {
        gemm_core<false, false, float>(blockIdx.x, x, w1hi, w1lo, nullptr, g);
    } else {
        int tid = (blockIdx.x - GEMM_GRID) * 256 + threadIdx.x;
        place_core4(tid, row, col, ew, cursor64, epk);
    }
}

// layer-2 GEMM wrapper (dis folded in epilogue)
__global__ __launch_bounds__(256, 2) void gemm2(const _Float16* __restrict__ in,
                                                const unsigned short* __restrict__ whi,
                                                const unsigned short* __restrict__ wlo,
                                                const float* __restrict__ dis,
                                                _Float16* __restrict__ out) {
    gemm_core<true, true, _Float16>(blockIdx.x, in, whi, wlo, dis, out);
}

// ---------------- node_dis + g1 scaling: dis, endarr, g1 *= dis ----------------

__global__ __launch_bounds__(256) void node_dis_scale(const unsigned long long* __restrict__ cursor64,
                                                      float* __restrict__ dis,
                                                      int* __restrict__ endarr,
                                                      _Float16* __restrict__ g) {
    int t = blockIdx.x * blockDim.x + threadIdx.x;
    int i = t >> 4, sub = t & 15;
    if (i >= NN) return;
    unsigned long long cv = cursor64[i * QPAD];    // broadcast across the 16 lanes
    float deg = 1.0f + (float)(cv & LOW40) * (1.0f / FIX_SCALE);  // +1 self-loop
    float d = rsqrtf(deg);
    if (sub == 0) {
        dis[i] = d;
        endarr[i] = (i << 6) + min((int)(cv >> 40), CAP);
    }
    half8* gp = (half8*)(g + (size_t)i * DD + sub * 8);
    half8 v = *gp;
#pragma unroll
    for (int j = 0; j < 8; j++) v[j] = (_Float16)((float)v[j] * d);
    *gp = v;
}

// ---------------- bucket gather aggregation (fp16 g, f32 accumulate) ----------------
// One wave per node; half-waves on alternating slots, 4x unrolled -> 8 gathers in flight.
// out[i] = b + dis_i * (sum_e ew_e * g[row_e] + g[i]),  g = dis*h

template <typename OutT>
__global__ __launch_bounds__(256) void agg_half(const int* __restrict__ endarr,
                                                const uint2* __restrict__ epk,
                                                const _Float16* __restrict__ g,
                                                const float* __restrict__ dis,
                                                const float* __restrict__ bias,
                                                OutT* __restrict__ out) {
    int i = (blockIdx.x * blockDim.x + threadIdx.x) >> 6;   // node
    int lane = threadIdx.x & 63;
    int s = lane & 31;
    int half = lane >> 5;
    if (i >= NN) return;

    half4 gv = *(const half4*)(g + (size_t)i * DD + s * 4);  // self-loop term g_i
    float4 bb = ((const float4*)bias)[s];
    float d = dis[i];

    float ax = 0.0f, ay = 0.0f, az = 0.0f, aw = 0.0f;

    int start = i << 6;
    int end = endarr[i];
    int j = start + half;
    for (; j + 6 < end; j += 8) {
        uint2 p0 = epk[j], p1 = epk[j + 2], p2 = epk[j + 4], p3 = epk[j + 6];
        half4 v0 = *(const half4*)(g + p0.x + s * 4);
        half4 v1 = *(const half4*)(g + p1.x + s * 4);
        half4 v2 = *(const half4*)(g + p2.x + s * 4);
        half4 v3 = *(const half4*)(g + p3.x + s * 4);
        float n0 = __uint_as_float(p0.y), n1 = __uint_as_float(p1.y);
        float n2 = __uint_as_float(p2.y), n3 = __uint_as_float(p3.y);
        ax = fmaf(n0, (float)v0.x, ax); ay = fmaf(n0, (float)v0.y, ay);
        az = fmaf(n0, (float)v0.z, az); aw = fmaf(n0, (float)v0.w, aw);
        ax = fmaf(n1, (float)v1.x, ax); ay = fmaf(n1, (float)v1.y, ay);
        az = fmaf(n1, (float)v1.z, az); aw = fmaf(n1, (float)v1.w, aw);
        ax = fmaf(n2, (float)v2.x, ax); ay = fmaf(n2, (float)v2.y, ay);
        az = fmaf(n2, (float)v2.z, az); aw = fmaf(n2, (float)v2.w, aw);
        ax = fmaf(n3, (float)v3.x, ax); ay = fmaf(n3, (float)v3.y, ay);
        az = fmaf(n3, (float)v3.z, az); aw = fmaf(n3, (float)v3.w, aw);
    }
    for (; j < end; j += 2) {
        uint2 p = epk[j];
        float nm = __uint_as_float(p.y);
        half4 v = *(const half4*)(g + p.x + s * 4);
        ax = fmaf(nm, (float)v.x, ax); ay = fmaf(nm, (float)v.y, ay);
        az = fmaf(nm, (float)v.z, az); aw = fmaf(nm, (float)v.w, aw);
    }

    ax += __shfl_xor(ax, 32);
    ay += __shfl_xor(ay, 32);
    az += __shfl_xor(az, 32);
    aw += __shfl_xor(aw, 32);

    if (half == 0) {
        float ox = bb.x + d * (ax + (float)gv.x);
        float oy = bb.y + d * (ay + (float)gv.y);
        float oz = bb.z + d * (az + (float)gv.z);
        float ow = bb.w + d * (aw + (float)gv.w);
        if constexpr (sizeof(OutT) == 2) {
            half4 o;
            o.x = (_Float16)ox; o.y = (_Float16)oy;
            o.z = (_Float16)oz; o.w = (_Float16)ow;
            *(half4*)(out + (size_t)i * DD + s * 4) = o;
        } else {
            float4 o;
            o.x = ox; o.y = oy; o.z = oz; o.w = ow;
            ((float4*)(out + (size_t)i * DD))[s] = o;
        }
    }
}

// ---------------- launch ----------------

extern "C" void kernel_launch(void* const* d_in, const int* in_sizes, int n_in,
                              void* d_out, int out_size, void* d_ws, size_t ws_size,
                              hipStream_t stream) {
    const float* x  = (const float*)d_in[0];
    const int*   ei = (const int*)d_in[1];
    const float* ew = (const float*)d_in[2];
    const float* W1 = (const float*)d_in[3];
    const float* b1 = (const float*)d_in[4];
    const float* W2 = (const float*)d_in[5];
    const float* b2 = (const float*)d_in[6];
    float* out = (float*)d_out;

    // workspace layout (4B words)
    float* ws      = (float*)d_ws;
    float* dis     = ws;                                        // [0, 50000)
    int*   endarr  = (int*)(ws + 50000);                        // [50000, 100000)
    unsigned long long* cursor64 = (unsigned long long*)(ws + 100000);  // NN*QPAD ull = 800000 words
    uint2* epk     = (uint2*)(ws + 900000);                     // NN*CAP uint2 = 6.4M words
    _Float16* gbuf = (_Float16*)(ws + 7300000);                 // NN*DD fp16 = 3.2M words
    unsigned short* wt1hi = (unsigned short*)(ws + 10500000);   // 8192 words each
    unsigned short* wt1lo = (unsigned short*)(ws + 10508192);
    unsigned short* wt2hi = (unsigned short*)(ws + 10516384);
    unsigned short* wt2lo = (unsigned short*)(ws + 10524576);
    _Float16* out1 = (_Float16*)(ws + 10532768);                // NN*DD fp16 = 3.2M words
    // total ~13.73M words ~= 54.9 MB

    const int* rowi = ei;
    const int* coli = ei + NE;

    // ---- 1: zero bins + split W1/W2 ----
    init_prep<<<(NN + 2 * NWELEM + 255) / 256, 256, 0, stream>>>(
        cursor64, W1, W2, wt1hi, wt1lo, wt2hi, wt2lo);

    // ---- 2: FUSED gemm1 (h1 = x@W1, unscaled) + edge placement (4 edges/thread) ----
    gemm1_place<<<GEMM_GRID + PLACE_GRID, 256, 0, stream>>>(
        x, wt1hi, wt1lo, gbuf, rowi, coli, ew, cursor64, epk);

    // ---- 3: dis/endarr + g1 *= dis ----
    node_dis_scale<<<(NN * 16) / 256, 256, 0, stream>>>(cursor64, dis, endarr, gbuf);

    const int agg_grid = (NN * 64) / 256 + 1;

    // ---- 4: out1 = b1 + dis*(edge_sum + g1)  (fp16) ----
    agg_half<_Float16><<<agg_grid, 256, 0, stream>>>(endarr, epk, gbuf, dis, b1, out1);

    // ---- 5: g2 = (relu(out1)@W2)*dis  (fp16) ----
    gemm2<<<GEMM_GRID, 256, 0, stream>>>(out1, wt2hi, wt2lo, dis, gbuf);

    // ---- 6: out = b2 + dis*(edge_sum + g2)  (f32) ----
    agg_half<float><<<agg_grid, 256, 0, stream>>>(endarr, epk, gbuf, dis, b2, out);
}

// Round 16
// 231.629 us; speedup vs baseline: 1.1922x; 1.0219x over previous
//
#include <hip/hip_runtime.h>

#define NN 50000
#define NE 800000
#define DD 128

#define CAP 64                                     // slots per node bucket
#define QPAD 8                                     // cursor64: 1 bin per 64B
#define FIX_SCALE 16777216.0f                      // 2^24
#define LOW40 ((1ULL << 40) - 1)
#define NWELEM 16384                               // per weight matrix
#define GEMM_GRID ((NN + 127) / 128)               // 391
#define EPT 4                                      // edges per place thread
#define PLACE_T (NE / EPT)                         // 200000 place threads
#define PLACE_GRID ((PLACE_T + 255) / 256)         // 782

typedef __attribute__((ext_vector_type(8))) short short8;
typedef __attribute__((ext_vector_type(4))) float floatx4;
typedef __attribute__((ext_vector_type(4))) _Float16 half4;
typedef __attribute__((ext_vector_type(8))) _Float16 half8;

// ---------------- fp16 <-> bits helpers ----------------

__device__ __forceinline__ unsigned f2h_bits(float x) {
    _Float16 h = (_Float16)x;
    unsigned short us;
    __builtin_memcpy(&us, &h, 2);
    return (unsigned)us;
}

__device__ __forceinline__ float h_bits2f(unsigned v) {
    unsigned short us = (unsigned short)v;
    _Float16 h;
    __builtin_memcpy(&h, &us, 2);
    return (float)h;
}

// ---------------- bf16 split (truncation; err ~2^-16 rel) ----------------

__device__ __forceinline__ void split_trunc(float x, short& hi, short& lo) {
    unsigned uh = __float_as_uint(x) >> 16;
    hi = (short)uh;
    float r = x - __uint_as_float(uh << 16);
    lo = (short)(__float_as_uint(r) >> 16);
}

// ---------------- fused init: zero atomic bins + split both W matrices ----------------

__global__ void init_prep(unsigned long long* __restrict__ cursor64,
                          const float* __restrict__ W1, const float* __restrict__ W2,
                          unsigned short* __restrict__ w1hi, unsigned short* __restrict__ w1lo,
                          unsigned short* __restrict__ w2hi, unsigned short* __restrict__ w2lo) {
    int t = blockIdx.x * blockDim.x + threadIdx.x;
    if (t < NN) cursor64[t * QPAD] = 0ULL;
    int u = t - NN;
    if (u >= 0 && u < 2 * NWELEM) {
        int which = u >> 14;
        int idx = u & (NWELEM - 1);
        int k = idx >> 7, n = idx & 127;
        const float* W = which ? W2 : W1;
        unsigned short* whi = which ? w2hi : w1hi;
        unsigned short* wlo = which ? w2lo : w1lo;
        short h, l;
        split_trunc(W[idx], h, l);
        whi[n * DD + k] = (unsigned short)h;
        wlo[n * DD + k] = (unsigned short)l;
    }
}

// ---------------- GEMM core: out[m,128] (fp16) = (relu?)in @ W (*dis?) ----------------

template <bool RELU, bool SCALE, typename InT>
__device__ __forceinline__ void gemm_core(int bid, const InT* __restrict__ in,
                                          const unsigned short* __restrict__ whi,
                                          const unsigned short* __restrict__ wlo,
                                          const float* __restrict__ dis,
                                          _Float16* __restrict__ out) {
    int lane = threadIdx.x & 63;
    int wid = threadIdx.x >> 6;
    int cg = wid & 1;
    int rg = wid >> 1;
    int l16 = lane & 15;
    int quad = lane >> 4;
    int koff_base = quad * 8;

    short8 bhi[4][4], blo[4][4];
#pragma unroll
    for (int t = 0; t < 4; t++) {
        int n = cg * 64 + t * 16 + l16;
#pragma unroll
        for (int ks = 0; ks < 4; ks++) {
            int koff = ks * 32 + koff_base;
            bhi[t][ks] = *(const short8*)(whi + n * DD + koff);
            blo[t][ks] = *(const short8*)(wlo + n * DD + koff);
        }
    }

#pragma unroll
    for (int chunk = 0; chunk < 4; chunk++) {
        int base = bid * 128 + chunk * 32 + rg * 16;
        int m = base + l16;
        int mld = (m < NN) ? m : 0;
        const InT* xr = in + (size_t)mld * DD;

        short8 ahi[4], alo[4];
#pragma unroll
        for (int ks = 0; ks < 4; ks++) {
            int koff = ks * 32 + koff_base;
            float v[8];
            if constexpr (sizeof(InT) == 4) {
                float4 a0 = *(const float4*)(xr + koff);
                float4 a1 = *(const float4*)(xr + koff + 4);
                v[0] = a0.x; v[1] = a0.y; v[2] = a0.z; v[3] = a0.w;
                v[4] = a1.x; v[5] = a1.y; v[6] = a1.z; v[7] = a1.w;
            } else {
                half8 a = *(const half8*)(xr + koff);
#pragma unroll
                for (int j = 0; j < 8; j++) v[j] = (float)a[j];
            }
#pragma unroll
            for (int j = 0; j < 8; j++) {
                float xv = RELU ? fmaxf(v[j], 0.0f) : v[j];
                short h, l;
                split_trunc(xv, h, l);
                ahi[ks][j] = h;
                alo[ks][j] = l;
            }
        }

        floatx4 acc[4];
#pragma unroll
        for (int t = 0; t < 4; t++) acc[t] = (floatx4)(0.0f);

#pragma unroll
        for (int ks = 0; ks < 4; ks++) {
#pragma unroll
            for (int t = 0; t < 4; t++) {
                acc[t] = __builtin_amdgcn_mfma_f32_16x16x32_bf16(ahi[ks], bhi[t][ks], acc[t], 0, 0, 0);
                acc[t] = __builtin_amdgcn_mfma_f32_16x16x32_bf16(alo[ks], bhi[t][ks], acc[t], 0, 0, 0);
                acc[t] = __builtin_amdgcn_mfma_f32_16x16x32_bf16(ahi[ks], blo[t][ks], acc[t], 0, 0, 0);
            }
        }

#pragma unroll
        for (int r = 0; r < 4; r++) {
            int rowm = base + quad * 4 + r;
            if (rowm < NN) {
                float dsc = SCALE ? dis[rowm] : 1.0f;
                _Float16* o = out + (size_t)rowm * DD + cg * 64 + l16;
#pragma unroll
                for (int t = 0; t < 4; t++) o[t * 16] = (_Float16)(acc[t][r] * dsc);
            }
        }
    }
}

// ---------------- placement core: EPT edges/thread; 4B packed epk (row:16 | fp16 ew) ----------------

__device__ __forceinline__ void place_core4(int tid, const int* __restrict__ row,
                                            const int* __restrict__ col,
                                            const float* __restrict__ ew,
                                            unsigned long long* __restrict__ cursor64,
                                            unsigned* __restrict__ epk) {
    if (tid >= PLACE_T) return;
    int c[EPT], r[EPT];
    float w[EPT];
    unsigned long long old[EPT];
#pragma unroll
    for (int k = 0; k < EPT; k++) {
        int e = tid + k * PLACE_T;                 // coalesced within wave
        c[k] = col[e];
        r[k] = row[e];
        w[k] = ew[e];
    }
#pragma unroll
    for (int k = 0; k < EPT; k++) {
        unsigned q = (unsigned)(w[k] * FIX_SCALE + 0.5f);   // full-precision deg accum
        old[k] = atomicAdd(&cursor64[c[k] * QPAD], (1ULL << 40) | (unsigned long long)q);
    }
#pragma unroll
    for (int k = 0; k < EPT; k++) {
        int rank = min((int)(old[k] >> 40), CAP - 1);       // clamp: memory safety
        epk[(c[k] << 6) + rank] = ((unsigned)r[k] << 16) | f2h_bits(w[k]);
    }
}

// ---------------- FUSED: gemm1 (independent of graph) + edge placement ----------------

__global__ __launch_bounds__(256) void gemm1_place(const float* __restrict__ x,
                                                   const unsigned short* __restrict__ w1hi,
                                                   const unsigned short* __restrict__ w1lo,
                                                   _Float16* __restrict__ g,
                                                   const int* __restrict__ row,
                                                   const int* __restrict__ col,
                                                   const float* __restrict__ ew,
                                                   unsigned long long* __restrict__ cursor64,
                                                   unsigned* __restrict__ epk) {
    if (blockIdx.x < GEMM_GRID) {
        gemm_core<false, false, float>(blockIdx.x, x, w1hi, w1lo, nullptr, g);
    } else {
        int tid = (blockIdx.x - GEMM_GRID) * 256 + threadIdx.x;
        place_core4(tid, row, col, ew, cursor64, epk);
    }
}

// layer-2 GEMM wrapper (dis folded in epilogue)
__global__ __launch_bounds__(256, 2) void gemm2(const _Float16* __restrict__ in,
                                                const unsigned short* __restrict__ whi,
                                                const unsigned short* __restrict__ wlo,
                                                const float* __restrict__ dis,
                                                _Float16* __restrict__ out) {
    gemm_core<true, true, _Float16>(blockIdx.x, in, whi, wlo, dis, out);
}

// ---------------- node_dis + g1 scaling: dis, endarr, g1 *= dis ----------------

__global__ __launch_bounds__(256) void node_dis_scale(const unsigned long long* __restrict__ cursor64,
                                                      float* __restrict__ dis,
                                                      int* __restrict__ endarr,
                                                      _Float16* __restrict__ g) {
    int t = blockIdx.x * blockDim.x + threadIdx.x;
    int i = t >> 4, sub = t & 15;
    if (i >= NN) return;
    unsigned long long cv = cursor64[i * QPAD];    // broadcast across the 16 lanes
    float deg = 1.0f + (float)(cv & LOW40) * (1.0f / FIX_SCALE);  // +1 self-loop
    float d = rsqrtf(deg);
    if (sub == 0) {
        dis[i] = d;
        endarr[i] = (i << 6) + min((int)(cv >> 40), CAP);
    }
    half8* gp = (half8*)(g + (size_t)i * DD + sub * 8);
    half8 v = *gp;
#pragma unroll
    for (int j = 0; j < 8; j++) v[j] = (_Float16)((float)v[j] * d);
    *gp = v;
}

// ---------------- bucket gather aggregation (fp16 g, f32 accumulate) ----------------
// One wave per node; half-waves on alternating slots, 4x unrolled -> 8 gathers in flight.
// epk entry: (row:16 | fp16 ew). out[i] = b + dis_i * (sum ew*g[row] + g[i]), g = dis*h

template <typename OutT>
__global__ __launch_bounds__(256) void agg_half(const int* __restrict__ endarr,
                                                const unsigned* __restrict__ epk,
                                                const _Float16* __restrict__ g,
                                                const float* __restrict__ dis,
                                                const float* __restrict__ bias,
                                                OutT* __restrict__ out) {
    int i = (blockIdx.x * blockDim.x + threadIdx.x) >> 6;   // node
    int lane = threadIdx.x & 63;
    int s = lane & 31;
    int half = lane >> 5;
    if (i >= NN) return;

    half4 gv = *(const half4*)(g + (size_t)i * DD + s * 4);  // self-loop term g_i
    float4 bb = ((const float4*)bias)[s];
    float d = dis[i];

    float ax = 0.0f, ay = 0.0f, az = 0.0f, aw = 0.0f;

    int start = i << 6;
    int end = endarr[i];
    int j = start + half;
    for (; j + 6 < end; j += 8) {
        unsigned p0 = epk[j], p1 = epk[j + 2], p2 = epk[j + 4], p3 = epk[j + 6];
        half4 v0 = *(const half4*)(g + ((size_t)(p0 >> 16) << 7) + s * 4);
        half4 v1 = *(const half4*)(g + ((size_t)(p1 >> 16) << 7) + s * 4);
        half4 v2 = *(const half4*)(g + ((size_t)(p2 >> 16) << 7) + s * 4);
        half4 v3 = *(const half4*)(g + ((size_t)(p3 >> 16) << 7) + s * 4);
        float n0 = h_bits2f(p0 & 0xFFFFu), n1 = h_bits2f(p1 & 0xFFFFu);
        float n2 = h_bits2f(p2 & 0xFFFFu), n3 = h_bits2f(p3 & 0xFFFFu);
        ax = fmaf(n0, (float)v0.x, ax); ay = fmaf(n0, (float)v0.y, ay);
        az = fmaf(n0, (float)v0.z, az); aw = fmaf(n0, (float)v0.w, aw);
        ax = fmaf(n1, (float)v1.x, ax); ay = fmaf(n1, (float)v1.y, ay);
        az = fmaf(n1, (float)v1.z, az); aw = fmaf(n1, (float)v1.w, aw);
        ax = fmaf(n2, (float)v2.x, ax); ay = fmaf(n2, (float)v2.y, ay);
        az = fmaf(n2, (float)v2.z, az); aw = fmaf(n2, (float)v2.w, aw);
        ax = fmaf(n3, (float)v3.x, ax); ay = fmaf(n3, (float)v3.y, ay);
        az = fmaf(n3, (float)v3.z, az); aw = fmaf(n3, (float)v3.w, aw);
    }
    for (; j < end; j += 2) {
        unsigned p = epk[j];
        float nm = h_bits2f(p & 0xFFFFu);
        half4 v = *(const half4*)(g + ((size_t)(p >> 16) << 7) + s * 4);
        ax = fmaf(nm, (float)v.x, ax); ay = fmaf(nm, (float)v.y, ay);
        az = fmaf(nm, (float)v.z, az); aw = fmaf(nm, (float)v.w, aw);
    }

    ax += __shfl_xor(ax, 32);
    ay += __shfl_xor(ay, 32);
    az += __shfl_xor(az, 32);
    aw += __shfl_xor(aw, 32);

    if (half == 0) {
        float ox = bb.x + d * (ax + (float)gv.x);
        float oy = bb.y + d * (ay + (float)gv.y);
        float oz = bb.z + d * (az + (float)gv.z);
        float ow = bb.w + d * (aw + (float)gv.w);
        if constexpr (sizeof(OutT) == 2) {
            half4 o;
            o.x = (_Float16)ox; o.y = (_Float16)oy;
            o.z = (_Float16)oz; o.w = (_Float16)ow;
            *(half4*)(out + (size_t)i * DD + s * 4) = o;
        } else {
            float4 o;
            o.x = ox; o.y = oy; o.z = oz; o.w = ow;
            ((float4*)(out + (size_t)i * DD))[s] = o;
        }
    }
}

// ---------------- launch ----------------

extern "C" void kernel_launch(void* const* d_in, const int* in_sizes, int n_in,
                              void* d_out, int out_size, void* d_ws, size_t ws_size,
                              hipStream_t stream) {
    const float* x  = (const float*)d_in[0];
    const int*   ei = (const int*)d_in[1];
    const float* ew = (const float*)d_in[2];
    const float* W1 = (const float*)d_in[3];
    const float* b1 = (const float*)d_in[4];
    const float* W2 = (const float*)d_in[5];
    const float* b2 = (const float*)d_in[6];
    float* out = (float*)d_out;

    // workspace layout (4B words)
    float* ws      = (float*)d_ws;
    float* dis     = ws;                                        // [0, 50000)
    int*   endarr  = (int*)(ws + 50000);                        // [50000, 100000)
    unsigned long long* cursor64 = (unsigned long long*)(ws + 100000);  // NN*QPAD ull = 800000 words
    unsigned* epk  = (unsigned*)(ws + 900000);                  // NN*CAP uint = 3.2M words
    _Float16* gbuf = (_Float16*)(ws + 4100000);                 // NN*DD fp16 = 3.2M words
    unsigned short* wt1hi = (unsigned short*)(ws + 7300000);    // 8192 words each
    unsigned short* wt1lo = (unsigned short*)(ws + 7308192);
    unsigned short* wt2hi = (unsigned short*)(ws + 7316384);
    unsigned short* wt2lo = (unsigned short*)(ws + 7324576);
    _Float16* out1 = (_Float16*)(ws + 7332768);                 // NN*DD fp16 = 3.2M words
    // total ~10.5M words ~= 42 MB

    const int* rowi = ei;
    const int* coli = ei + NE;

    // ---- 1: zero bins + split W1/W2 ----
    init_prep<<<(NN + 2 * NWELEM + 255) / 256, 256, 0, stream>>>(
        cursor64, W1, W2, wt1hi, wt1lo, wt2hi, wt2lo);

    // ---- 2: FUSED gemm1 (h1 = x@W1, unscaled) + edge placement (4B packed) ----
    gemm1_place<<<GEMM_GRID + PLACE_GRID, 256, 0, stream>>>(
        x, wt1hi, wt1lo, gbuf, rowi, coli, ew, cursor64, epk);

    // ---- 3: dis/endarr + g1 *= dis ----
    node_dis_scale<<<(NN * 16) / 256, 256, 0, stream>>>(cursor64, dis, endarr, gbuf);

    const int agg_grid = (NN * 64) / 256 + 1;

    // ---- 4: out1 = b1 + dis*(edge_sum + g1)  (fp16) ----
    agg_half<_Float16><<<agg_grid, 256, 0, stream>>>(endarr, epk, gbuf, dis, b1, out1);

    // ---- 5: g2 = (relu(out1)@W2)*dis  (fp16) ----
    gemm2<<<GEMM_GRID, 256, 0, stream>>>(out1, wt2hi, wt2lo, dis, gbuf);

    // ---- 6: out = b2 + dis*(edge_sum + g2)  (f32) ----
    agg_half<float><<<agg_grid, 256, 0, stream>>>(endarr, epk, gbuf, dis, b2, out);
}